// Round 5
// baseline (589.546 us; speedup 1.0000x reference)
//
#include <hip/hip_runtime.h>
#include <math.h>

// PathPreservingNetwork — factored-class + bf16x3 MFMA, R5.
// Classes per layer input: 1,1,3,7,15,31; every path value is s*C[class].
// R5: split-K fixup fusion (last-arriver combines, Tensile GSU pattern),
// rownorm fused into L4 epilogue, stats fused into L5 epilogue (atomics;
// one shared key per class => prune ties stay exact), packx merged into
// transW, BK=64 for the long-K kernels. 11 launches total.

using s8v = __attribute__((ext_vector_type(8))) short;
using f4v = __attribute__((ext_vector_type(4))) float;

__device__ __forceinline__ float bf2f(short b) {
  unsigned u = ((unsigned)(unsigned short)b) << 16;
  return __builtin_bit_cast(float, u);
}
__device__ __forceinline__ short f2bf(float f) {
  unsigned u = __builtin_bit_cast(unsigned, f);
  u = (u + 0x7FFFu + ((u >> 16) & 1u)) >> 16;
  return (short)u;
}
__device__ __forceinline__ void split_store(float f, short* hi, short* lo) {
  short h = f2bf(f);
  *hi = h;
  *lo = f2bf(f - bf2f(h));
}

// Zero ns/dotv/nrmv/cnt zone: exactly 12288 floats (48 blocks x 256).
__global__ void __launch_bounds__(256)
zero_zone(float* __restrict__ z) {
  z[blockIdx.x * 256 + threadIdx.x] = 0.f;
}

// Transpose+split all six W -> (N x 1024 bf16 hi/lo); z==6 packs x.
struct TWArgs {
  const float* W[6];
  short* Th[6];
  short* Tl[6];
  const float* x;
  short* A0h;
  short* A0l;
};
__global__ void __launch_bounds__(256)
transW_all(TWArgs a) {
  const int z = blockIdx.z;
  const int t = threadIdx.x;
  if (z == 6) {  // pack x (128x1024 fp32 -> hi/lo)
    int bid = blockIdx.y * 16 + blockIdx.x;
    if (bid >= 128) return;
    int i = (bid * 256 + t) * 4;
    float4 v = *(const float4*)&a.x[i];
    short4 h, l;
    h.x = f2bf(v.x); l.x = f2bf(v.x - bf2f(h.x));
    h.y = f2bf(v.y); l.y = f2bf(v.y - bf2f(h.y));
    h.z = f2bf(v.z); l.z = f2bf(v.z - bf2f(h.z));
    h.w = f2bf(v.w); l.w = f2bf(v.w - bf2f(h.w));
    *(short4*)&a.A0h[i] = h;
    *(short4*)&a.A0l[i] = l;
    return;
  }
  const int N = (z == 5) ? 512 : 1024;
  const int n0 = blockIdx.x * 64, k0 = blockIdx.y * 64;
  if (n0 >= N) return;
  const float* __restrict__ W = a.W[z];
  short* __restrict__ Th = a.Th[z];
  short* __restrict__ Tl = a.Tl[z];
  __shared__ float tile[64][65];
  const int r = t >> 4, c4 = (t & 15) * 4;
#pragma unroll
  for (int i = 0; i < 4; ++i) {
    int rr = r + 16 * i;
    float4 v = *(const float4*)&W[(size_t)(k0 + rr) * N + n0 + c4];
    tile[rr][c4 + 0] = v.x;
    tile[rr][c4 + 1] = v.y;
    tile[rr][c4 + 2] = v.z;
    tile[rr][c4 + 3] = v.w;
  }
  __syncthreads();
#pragma unroll
  for (int i = 0; i < 4; ++i) {
    int n = r + 16 * i;
    short4 h, l;
    float f0 = tile[c4 + 0][n], f1 = tile[c4 + 1][n];
    float f2 = tile[c4 + 2][n], f3 = tile[c4 + 3][n];
    h.x = f2bf(f0); l.x = f2bf(f0 - bf2f(h.x));
    h.y = f2bf(f1); l.y = f2bf(f1 - bf2f(h.y));
    h.z = f2bf(f2); l.z = f2bf(f2 - bf2f(h.z));
    h.w = f2bf(f3); l.w = f2bf(f3 - bf2f(h.w));
    size_t o = (size_t)(n0 + n) * 1024 + k0 + c4;
    *(short4*)&Th[o] = h;
    *(short4*)&Tl[o] = l;
  }
}

// ------------------------------------------------------------- MFMA GEMM ----
// A (M x 1024) hi/lo bf16 row-major; Wt (N x 1024) hi/lo bf16 row-major.
// Block tile 64x64, 4 waves 2x2, wave tile 32x32. bf16x3 (ah*bh+ah*bl+al*bh).
// EPI 0: L0   — out row rr = tanh(bias+acc), hi/lo. (split-K fixup)
// EPI 1: L1-3 — rows b*Dn+1+2u / +2+2u = tanh(bias -/+ acc) + zero row at
//               u==0, hi/lo. (split-K fixup)
// EPI 2: L4   — EPI1 stores + per-row sumsq atomics into ns (prune keys).
// EPI 3: L5   — raw fp32 out + per-row ||Y||^2 / dot(b5,Y) atomics.
template <int EPI, int D, int KS, int BK>
__global__ void __launch_bounds__(256, 2)
mfma_gemm(const short* __restrict__ Ah, const short* __restrict__ Al,
          const short* __restrict__ Bh, const short* __restrict__ Bl,
          const float* __restrict__ bias, short* __restrict__ Oh,
          short* __restrict__ Ol, float* __restrict__ Of,
          float* __restrict__ P, int* __restrict__ cnt,
          float* __restrict__ ns, float* __restrict__ dotv,
          float* __restrict__ nrmv, int N, int Dn) {
  constexpr int KC = 1024 / KS;
  constexpr int BKP = BK + 8;   // shorts; multiple of 8 -> 16B-aligned frags
  constexpr int NL = BK / 32;   // uint4 loads per array per thread per slab
  __shared__ short As_h[64 * BKP], As_l[64 * BKP];
  __shared__ short Bs_h[64 * BKP], Bs_l[64 * BKP];
  const int t = threadIdx.x;
  const int row0 = blockIdx.y * 64;
  const int col0 = blockIdx.x * 64;
  const int kb = blockIdx.z * KC;
  const int sr = t >> 2, sk0 = (t & 3) * (8 * NL);
  const short* Ahp = Ah + (size_t)(row0 + sr) * 1024 + kb + sk0;
  const short* Alp = Al + (size_t)(row0 + sr) * 1024 + kb + sk0;
  const short* Bhp = Bh + (size_t)(col0 + sr) * 1024 + kb + sk0;
  const short* Blp = Bl + (size_t)(col0 + sr) * 1024 + kb + sk0;
  const int w = t >> 6, lane = t & 63;
  const int l16 = lane & 15, q = lane >> 4;
  const int wm0 = (w & 1) * 32, wn0 = (w >> 1) * 32;
  f4v acc[2][2];
#pragma unroll
  for (int i = 0; i < 2; ++i)
#pragma unroll
    for (int j = 0; j < 2; ++j) acc[i][j] = (f4v){0.f, 0.f, 0.f, 0.f};
  uint4 rah[NL], ral[NL], rbh[NL], rbl[NL];
#pragma unroll
  for (int j = 0; j < NL; ++j) {
    rah[j] = *(const uint4*)(Ahp + 8 * j);
    ral[j] = *(const uint4*)(Alp + 8 * j);
    rbh[j] = *(const uint4*)(Bhp + 8 * j);
    rbl[j] = *(const uint4*)(Blp + 8 * j);
  }
  for (int k0 = 0; k0 < KC; k0 += BK) {
    __syncthreads();
#pragma unroll
    for (int j = 0; j < NL; ++j) {
      *(uint4*)&As_h[sr * BKP + sk0 + 8 * j] = rah[j];
      *(uint4*)&As_l[sr * BKP + sk0 + 8 * j] = ral[j];
      *(uint4*)&Bs_h[sr * BKP + sk0 + 8 * j] = rbh[j];
      *(uint4*)&Bs_l[sr * BKP + sk0 + 8 * j] = rbl[j];
    }
    if (k0 + BK < KC) {
#pragma unroll
      for (int j = 0; j < NL; ++j) {
        rah[j] = *(const uint4*)(Ahp + k0 + BK + 8 * j);
        ral[j] = *(const uint4*)(Alp + k0 + BK + 8 * j);
        rbh[j] = *(const uint4*)(Bhp + k0 + BK + 8 * j);
        rbl[j] = *(const uint4*)(Blp + k0 + BK + 8 * j);
      }
    }
    __syncthreads();
#pragma unroll
    for (int kk = 0; kk < BK / 32; ++kk) {
      s8v ah[2], al[2], bh[2], bl[2];
#pragma unroll
      for (int mt = 0; mt < 2; ++mt) {
        int o = (wm0 + mt * 16 + l16) * BKP + kk * 32 + q * 8;
        ah[mt] = *(const s8v*)&As_h[o];
        al[mt] = *(const s8v*)&As_l[o];
      }
#pragma unroll
      for (int nt = 0; nt < 2; ++nt) {
        int o = (wn0 + nt * 16 + l16) * BKP + kk * 32 + q * 8;
        bh[nt] = *(const s8v*)&Bs_h[o];
        bl[nt] = *(const s8v*)&Bs_l[o];
      }
#pragma unroll
      for (int mt = 0; mt < 2; ++mt)
#pragma unroll
        for (int nt = 0; nt < 2; ++nt) {
          acc[mt][nt] = __builtin_amdgcn_mfma_f32_16x16x32_bf16(
              ah[mt], bh[nt], acc[mt][nt], 0, 0, 0);
          acc[mt][nt] = __builtin_amdgcn_mfma_f32_16x16x32_bf16(
              ah[mt], bl[nt], acc[mt][nt], 0, 0, 0);
          acc[mt][nt] = __builtin_amdgcn_mfma_f32_16x16x32_bf16(
              al[mt], bh[nt], acc[mt][nt], 0, 0, 0);
        }
    }
  }

  // ------------------ split-K fixup: last-arriving block combines ----------
  if constexpr (KS > 1) {
    const int tile = blockIdx.y * gridDim.x + blockIdx.x;
    float* Pt = P + ((size_t)tile * KS + blockIdx.z) * 4096;
#pragma unroll
    for (int mt = 0; mt < 2; ++mt)
#pragma unroll
      for (int nt = 0; nt < 2; ++nt)
#pragma unroll
        for (int r = 0; r < 4; ++r)
          Pt[(wm0 + mt * 16 + q * 4 + r) * 64 + wn0 + nt * 16 + l16] =
              acc[mt][nt][r];
    __threadfence();  // release: writeback L2 so peers see partials
    __syncthreads();
    __shared__ int lastf;
    if (t == 0) lastf = (atomicAdd(&cnt[tile], 1) == KS - 1) ? 1 : 0;
    __syncthreads();
    if (!lastf) return;
    __threadfence();  // acquire: invalidate L2 before reading peer partials
#pragma unroll
    for (int mt = 0; mt < 2; ++mt)
#pragma unroll
      for (int nt = 0; nt < 2; ++nt)
#pragma unroll
        for (int r = 0; r < 4; ++r) {
          float s = 0.f;
          for (int sK = 0; sK < KS; ++sK)
            s += P[((size_t)tile * KS + sK) * 4096 +
                   (wm0 + mt * 16 + q * 4 + r) * 64 + wn0 + nt * 16 + l16];
          acc[mt][nt][r] = s;
        }
  }

  // ------------------------------- epilogues -------------------------------
  if constexpr (EPI == 0) {
#pragma unroll
    for (int nt = 0; nt < 2; ++nt) {
      int gcol = col0 + wn0 + nt * 16 + l16;
      float bc = bias[gcol];
#pragma unroll
      for (int mt = 0; mt < 2; ++mt)
#pragma unroll
        for (int r = 0; r < 4; ++r) {
          int rr = row0 + wm0 + mt * 16 + q * 4 + r;
          float tv = tanhf(bc + acc[mt][nt][r]);
          size_t o = (size_t)rr * N + gcol;
          split_store(tv, &Oh[o], &Ol[o]);
        }
    }
  } else if constexpr (EPI == 1) {
#pragma unroll
    for (int nt = 0; nt < 2; ++nt) {
      int gcol = col0 + wn0 + nt * 16 + l16;
      float bc = bias[gcol];
#pragma unroll
      for (int mt = 0; mt < 2; ++mt)
#pragma unroll
        for (int r = 0; r < 4; ++r) {
          int rr = row0 + wm0 + mt * 16 + q * 4 + r;
          int b = rr / D, u = rr - b * D;
          float v = acc[mt][nt][r];
          size_t ob = (size_t)(b * Dn) * N + gcol;
          size_t om = ob + (size_t)(1 + 2 * u) * N;
          size_t op = ob + (size_t)(2 + 2 * u) * N;
          split_store(tanhf(bc - v), &Oh[om], &Ol[om]);
          split_store(tanhf(bc + v), &Oh[op], &Ol[op]);
          if (u == 0) split_store(tanhf(bc), &Oh[ob], &Ol[ob]);
        }
    }
  } else if constexpr (EPI == 2) {
    // L4: stores + per-row sumsq -> ns (keys for prune4). D=15, Dn=31, N=1024.
    float bcr[2];
    int gc[2];
#pragma unroll
    for (int nt = 0; nt < 2; ++nt) {
      gc[nt] = col0 + wn0 + nt * 16 + l16;
      bcr[nt] = bias[gc[nt]];
    }
#pragma unroll
    for (int mt = 0; mt < 2; ++mt)
#pragma unroll
      for (int r = 0; r < 4; ++r) {
        int rr = row0 + wm0 + mt * 16 + q * 4 + r;
        int b = rr / D, u = rr - b * D;
        size_t ob = (size_t)(b * Dn) * (size_t)N;
        size_t om = ob + (size_t)(1 + 2 * u) * N;
        size_t op = ob + (size_t)(2 + 2 * u) * N;
        float sm = 0.f, sp = 0.f;
#pragma unroll
        for (int nt = 0; nt < 2; ++nt) {
          float v = acc[mt][nt][r];
          float tm = tanhf(bcr[nt] - v), tp = tanhf(bcr[nt] + v);
          split_store(tm, &Oh[om + gc[nt]], &Ol[om + gc[nt]]);
          split_store(tp, &Oh[op + gc[nt]], &Ol[op + gc[nt]]);
          sm = fmaf(tm, tm, sm);
          sp = fmaf(tp, tp, sp);
        }
#pragma unroll
        for (int msk = 1; msk < 16; msk <<= 1) {
          sm += __shfl_xor(sm, msk);
          sp += __shfl_xor(sp, msk);
        }
        if (l16 == 0) {
          atomicAdd(&ns[b * Dn + 1 + 2 * u], sm);
          atomicAdd(&ns[b * Dn + 2 + 2 * u], sp);
        }
        if (u == 0) {
          float sz = 0.f;
#pragma unroll
          for (int nt = 0; nt < 2; ++nt) {
            float tz = tanhf(bcr[nt]);
            split_store(tz, &Oh[ob + gc[nt]], &Ol[ob + gc[nt]]);
            sz = fmaf(tz, tz, sz);
          }
#pragma unroll
          for (int msk = 1; msk < 16; msk <<= 1) sz += __shfl_xor(sz, msk);
          if (l16 == 0) atomicAdd(&ns[b * Dn], sz);
        }
      }
  } else {
    // L5: raw fp32 out + ||Y||^2 and dot(b5,Y) atomics. bias == b5, N=512.
    float b5r[2];
    int gc[2];
#pragma unroll
    for (int nt = 0; nt < 2; ++nt) {
      gc[nt] = col0 + wn0 + nt * 16 + l16;
      b5r[nt] = bias[gc[nt]];
    }
#pragma unroll
    for (int mt = 0; mt < 2; ++mt)
#pragma unroll
      for (int r = 0; r < 4; ++r) {
        int rr = row0 + wm0 + mt * 16 + q * 4 + r;
        float nr = 0.f, dt = 0.f;
#pragma unroll
        for (int nt = 0; nt < 2; ++nt) {
          float v = acc[mt][nt][r];
          Of[(size_t)rr * N + gc[nt]] = v;
          nr = fmaf(v, v, nr);
          dt = fmaf(v, b5r[nt], dt);
        }
#pragma unroll
        for (int msk = 1; msk < 16; msk <<= 1) {
          nr += __shfl_xor(nr, msk);
          dt += __shfl_xor(dt, msk);
        }
        if (l16 == 0) {
          atomicAdd(&nrmv[rr], nr);
          atomicAdd(&dotv[rr], dt);
        }
      }
  }
}

// Prune after layer 4: 243 entries e = 3*j + t4; class via base-3 digit fold.
__global__ void __launch_bounds__(256)
prune4_k(const float* __restrict__ ns, int* __restrict__ kept4) {
  int b = blockIdx.x, t = threadIdx.x;
  __shared__ float nss[31];
  __shared__ float key[243];
  __shared__ int cls[243];
  if (t < 31) nss[t] = ns[b * 31 + t];
  __syncthreads();
  if (t < 243) {
    int j = t / 3, t4 = t - 3 * j;
    int d0 = j / 27, d1 = (j / 9) % 3, d2 = (j / 3) % 3, d3 = j % 3;
    int u = 0;
    u = (d0 == 1) ? 0 : (1 + 2 * u + (d0 == 2));
    u = (d1 == 1) ? 0 : (1 + 2 * u + (d1 == 2));
    u = (d2 == 1) ? 0 : (1 + 2 * u + (d2 == 2));
    u = (d3 == 1) ? 0 : (1 + 2 * u + (d3 == 2));
    cls[t] = u;
    key[t] = (t4 == 1) ? 0.f : nss[u];
  }
  __syncthreads();
  if (t < 243) {
    float k = key[t];
    int rank = 0;
    for (int e = 0; e < 243; ++e) {
      float ke = key[e];
      rank += (ke > k) || (ke == k && e < t);
    }
    if (rank < 128) {
      int t4 = t - 3 * (t / 3);
      kept4[b * 128 + rank] = (cls[t] << 1) | (t4 == 2 ? 1 : 0);
    }
  }
}

// Final prune 384->128. nb5 computed in-block (deterministic). Keys per
// (class,sign) computed once -> exact ties.
__global__ void __launch_bounds__(384)
prune5_k(const float* __restrict__ dotv, const float* __restrict__ nrmv,
         const float* __restrict__ b5, const int* __restrict__ kept4,
         int* __restrict__ kept5) {
  int b = blockIdx.x, t = threadIdx.x;
  __shared__ float red[384];
  __shared__ float pns[128];
  __shared__ float key[384];
  float p = 0.f;
  for (int o = t; o < 512; o += 384) p = fmaf(b5[o], b5[o], p);
  red[t] = p;
  __syncthreads();
  if (t < 128) red[t] = red[t] + red[t + 128] + red[t + 256];
  __syncthreads();
  if (t < 64) red[t] += red[t + 64];
  __syncthreads();
  if (t < 32) red[t] += red[t + 32];
  __syncthreads();
  if (t < 16) red[t] += red[t + 16];
  __syncthreads();
  if (t < 8) red[t] += red[t + 8];
  __syncthreads();
  if (t < 4) red[t] += red[t + 4];
  __syncthreads();
  if (t < 2) red[t] += red[t + 2];
  __syncthreads();
  if (t == 0) red[0] += red[1];
  __syncthreads();
  float nb5 = red[0];
  if (t < 128) {
    int k4 = kept4[b * 128 + t];
    int c = k4 >> 1;
    float s = (k4 & 1) ? 1.f : -1.f;
    pns[t] = nb5 + nrmv[b * 31 + c] + s * 2.f * dotv[b * 31 + c];
  }
  __syncthreads();
  int m = t / 3, tt = t - 3 * m;
  key[t] = (tt == 1) ? 0.f : pns[m];
  __syncthreads();
  float k = key[t];
  int rank = 0;
  for (int e = 0; e < 384; ++e) {
    float ke = key[e];
    rank += (ke > k) || (ke == k && e < t);
  }
  if (rank < 128) kept5[b * 128 + rank] = (m << 1) | (tt == 2 ? 1 : 0);
}

// Final data (B,512,128) + argmax-|.| output (B,512).
__global__ void __launch_bounds__(256)
finalize_k(const float* __restrict__ Y5, const float* __restrict__ b5,
           const int* __restrict__ kept4, const int* __restrict__ kept5,
           float* __restrict__ out, float* __restrict__ dataout) {
  const int b = blockIdx.y;
  const int o0 = blockIdx.x * 64;
  __shared__ float Ys[31][65];
  __shared__ float bias_s[64];
  __shared__ float vt[64][130];
  __shared__ float ra[64][4];
  __shared__ float rv[64][4];
  const int t = threadIdx.x;
  for (int idx = t; idx < 31 * 64; idx += 256) {
    int c = idx >> 6, o = idx & 63;
    Ys[c][o] = Y5[((size_t)b * 31 + c) * 512 + o0 + o];
  }
  if (t < 64) bias_s[t] = b5[o0 + t];
  const int rr = t & 127, oh = t >> 7;
  int k5 = kept5[b * 128 + rr];
  int m = k5 >> 1;
  float sig = (k5 & 1) ? 1.f : -1.f;
  int k4 = kept4[b * 128 + m];
  int cc = k4 >> 1;
  float s4 = (k4 & 1) ? 1.f : -1.f;
  float afac = sig * s4;
  __syncthreads();
#pragma unroll
  for (int ol = 0; ol < 32; ++ol) {
    int o = oh * 32 + ol;
    float v = sig * bias_s[o] + afac * Ys[cc][o];
    dataout[((size_t)b * 512 + o0 + o) * 128 + rr] = v;
    vt[o][rr] = v;
  }
  __syncthreads();
  int o = t >> 2, q = t & 3;
  float bestv = vt[o][q * 32];
  float besta = fabsf(bestv);
  for (int i = 1; i < 32; ++i) {
    float v = vt[o][q * 32 + i];
    float a = fabsf(v);
    if (a > besta) {
      besta = a;
      bestv = v;
    }
  }
  ra[o][q] = besta;
  rv[o][q] = bestv;
  __syncthreads();
  if (t < 64) {
    float ba = ra[t][0], bv = rv[t][0];
#pragma unroll
    for (int qq = 1; qq < 4; ++qq) {
      if (ra[t][qq] > ba) {
        ba = ra[t][qq];
        bv = rv[t][qq];
      }
    }
    out[(size_t)b * 512 + o0 + t] = bv;
  }
}

extern "C" void kernel_launch(void* const* d_in, const int* in_sizes, int n_in,
                              void* d_out, int out_size, void* d_ws,
                              size_t ws_size, hipStream_t stream) {
  const float* x = (const float*)d_in[0];
  const float* Wt[6];
  const float* bs[6];
  for (int i = 0; i < 6; ++i) {
    Wt[i] = (const float*)d_in[1 + 2 * i];
    bs[i] = (const float*)d_in[2 + 2 * i];
  }
  char* base = (char*)d_ws;
  // Aliases lifetime-disjoint in stream order:
  //   PA (partials L0-L2, <=6 MB) over C4h/C4l (first written at L3 fixup)
  //   PB (partials L3, 7 MB)      over W0/W1   (dead after L1)
  //   C5h over W0..W1, C5l over W2..part-W3 (dead after L3)
  //   Y5 over C1..C4 (dead after L4)
  short* A0h = (short*)(base + 0);
  short* A0l = (short*)(base + 262144);
  short* Wh[6], *Wl[6];
  {
    size_t off = 524288;
    for (int i = 0; i < 6; ++i) {
      size_t sz = (i < 5) ? 2097152 : 1048576;
      Wh[i] = (short*)(base + off);
      Wl[i] = (short*)(base + off + sz);
      off += 2 * sz;
    }
  }
  short* C1h = (short*)(base + 23592960), *C1l = (short*)(base + 23855104);
  short* C2h = (short*)(base + 24117248), *C2l = (short*)(base + 24903680);
  short* C3h = (short*)(base + 25690112), *C3l = (short*)(base + 27525120);
  short* C4h = (short*)(base + 29360128), *C4l = (short*)(base + 33292288);
  short* C5h = (short*)(base + 524288);
  short* C5l = (short*)(base + 8912896);
  float* PA = (float*)(base + 29360128);
  float* PB = (float*)(base + 524288);
  float* Y5 = (float*)(base + 23592960);
  // zero zone: ns(3968) dotv(3968) nrmv(3968) cnt(384) = 12288 floats
  float* ns = (float*)(base + 37224448);
  float* dotv = ns + 3968;
  float* nrmv = dotv + 3968;
  int* cnt = (int*)(nrmv + 3968);
  int* kept4 = (int*)(base + 37273600);
  int* kept5 = (int*)(base + 37339136);
  float* outp = (float*)d_out;
  float* dataout = outp + 128 * 512;

  dim3 blk(256);
  zero_zone<<<dim3(48), blk, 0, stream>>>(ns);
  TWArgs twa;
  for (int i = 0; i < 6; ++i) {
    twa.W[i] = Wt[i];
    twa.Th[i] = Wh[i];
    twa.Tl[i] = Wl[i];
  }
  twa.x = x;
  twa.A0h = A0h;
  twa.A0l = A0l;
  transW_all<<<dim3(16, 16, 7), blk, 0, stream>>>(twa);

  // L0: x -> C1 (split-K 8, fixup). tiles 32, cnt slice [0,32)
  mfma_gemm<0, 1, 8, 32><<<dim3(16, 2, 8), blk, 0, stream>>>(
      A0h, A0l, Wh[0], Wl[0], bs[0], C1h, C1l, nullptr, PA, cnt, nullptr,
      nullptr, nullptr, 1024, 1);
  // L1: C1 -> C2 (split-K 8). tiles 32, cnt slice [32,64)
  mfma_gemm<1, 1, 8, 32><<<dim3(16, 2, 8), blk, 0, stream>>>(
      C1h, C1l, Wh[1], Wl[1], bs[1], C2h, C2l, nullptr, PA, cnt + 32, nullptr,
      nullptr, nullptr, 1024, 3);
  // L2: C2 (384) -> C3 (split-K 4). tiles 96, cnt slice [64,160)
  mfma_gemm<1, 3, 4, 64><<<dim3(16, 6, 4), blk, 0, stream>>>(
      C2h, C2l, Wh[2], Wl[2], bs[2], C3h, C3l, nullptr, PA, cnt + 64, nullptr,
      nullptr, nullptr, 1024, 7);
  // L3: C3 (896) -> C4 (split-K 2, partials in PB). tiles 224, cnt [160,384)
  mfma_gemm<1, 7, 2, 64><<<dim3(16, 14, 2), blk, 0, stream>>>(
      C3h, C3l, Wh[3], Wl[3], bs[3], C4h, C4l, nullptr, PB, cnt + 160, nullptr,
      nullptr, nullptr, 1024, 15);
  // L4: C4 (1920) -> C5 (3968) + ns sumsq atomics
  mfma_gemm<2, 15, 1, 64><<<dim3(16, 30), blk, 0, stream>>>(
      C4h, C4l, Wh[4], Wl[4], bs[4], C5h, C5l, nullptr, nullptr, nullptr, ns,
      nullptr, nullptr, 1024, 31);
  // Prune 243 -> 128
  prune4_k<<<dim3(128), blk, 0, stream>>>(ns, kept4);
  // L5: C5 -> Y5 raw fp32 (3968 x 512) + dot/nrm atomics
  mfma_gemm<3, 31, 1, 64><<<dim3(8, 62), blk, 0, stream>>>(
      C5h, C5l, Wh[5], Wl[5], bs[5], nullptr, nullptr, Y5, nullptr, nullptr,
      nullptr, dotv, nrmv, 512, 0);
  // Final prune + output
  prune5_k<<<dim3(128), dim3(384), 0, stream>>>(dotv, nrmv, bs[5], kept4,
                                                kept5);
  finalize_k<<<dim3(8, 128), blk, 0, stream>>>(Y5, bs[5], kept4, kept5, outp,
                                               dataout);
}

// Round 6
// 246.456 us; speedup vs baseline: 2.3921x; 2.3921x over previous
//
#include <hip/hip_runtime.h>
#include <math.h>

// PathPreservingNetwork — factored-class + bf16x3 MFMA, R6.
// Classes per layer input: 1,1,3,7,15,31; every path value is s*C[class].
// R6 = R4's proven GEMM structure (BK=32, split-K partials + separate combine
// kernels, NO device fences — R5 showed __threadfence == full-L2 wb/inv,
// 82 MB write amplification) + validated fusions: rownorm in L4 epilogue,
// stats in L5 epilogue (atomics; one shared key per class => ties exact),
// zero-zone + x-pack folded into transW. 14 launches.

using s8v = __attribute__((ext_vector_type(8))) short;
using f4v = __attribute__((ext_vector_type(4))) float;

__device__ __forceinline__ float bf2f(short b) {
  unsigned u = ((unsigned)(unsigned short)b) << 16;
  return __builtin_bit_cast(float, u);
}
__device__ __forceinline__ short f2bf(float f) {
  unsigned u = __builtin_bit_cast(unsigned, f);
  u = (u + 0x7FFFu + ((u >> 16) & 1u)) >> 16;
  return (short)u;
}
__device__ __forceinline__ void split_store(float f, short* hi, short* lo) {
  short h = f2bf(f);
  *hi = h;
  *lo = f2bf(f - bf2f(h));
}

// Transpose+split all six W -> (N x 1024 bf16 hi/lo). z==6: blocks 0..127
// pack x (fp32 -> hi/lo); blocks 128..175 zero the ns/dotv/nrmv zone.
struct TWArgs {
  const float* W[6];
  short* Th[6];
  short* Tl[6];
  const float* x;
  short* A0h;
  short* A0l;
  float* zone;  // 12288 floats: ns(3968) dotv(3968) nrmv(3968) + pad
};
__global__ void __launch_bounds__(256)
transW_all(TWArgs a) {
  const int z = blockIdx.z;
  const int t = threadIdx.x;
  if (z == 6) {
    int bid = blockIdx.y * 16 + blockIdx.x;
    if (bid < 128) {
      int i = (bid * 256 + t) * 4;
      float4 v = *(const float4*)&a.x[i];
      short4 h, l;
      h.x = f2bf(v.x); l.x = f2bf(v.x - bf2f(h.x));
      h.y = f2bf(v.y); l.y = f2bf(v.y - bf2f(h.y));
      h.z = f2bf(v.z); l.z = f2bf(v.z - bf2f(h.z));
      h.w = f2bf(v.w); l.w = f2bf(v.w - bf2f(h.w));
      *(short4*)&a.A0h[i] = h;
      *(short4*)&a.A0l[i] = l;
    } else if (bid < 176) {
      a.zone[(bid - 128) * 256 + t] = 0.f;
    }
    return;
  }
  const int N = (z == 5) ? 512 : 1024;
  const int n0 = blockIdx.x * 64, k0 = blockIdx.y * 64;
  if (n0 >= N) return;
  const float* __restrict__ W = a.W[z];
  short* __restrict__ Th = a.Th[z];
  short* __restrict__ Tl = a.Tl[z];
  __shared__ float tile[64][65];
  const int r = t >> 4, c4 = (t & 15) * 4;
#pragma unroll
  for (int i = 0; i < 4; ++i) {
    int rr = r + 16 * i;
    float4 v = *(const float4*)&W[(size_t)(k0 + rr) * N + n0 + c4];
    tile[rr][c4 + 0] = v.x;
    tile[rr][c4 + 1] = v.y;
    tile[rr][c4 + 2] = v.z;
    tile[rr][c4 + 3] = v.w;
  }
  __syncthreads();
#pragma unroll
  for (int i = 0; i < 4; ++i) {
    int n = r + 16 * i;
    short4 h, l;
    float f0 = tile[c4 + 0][n], f1 = tile[c4 + 1][n];
    float f2 = tile[c4 + 2][n], f3 = tile[c4 + 3][n];
    h.x = f2bf(f0); l.x = f2bf(f0 - bf2f(h.x));
    h.y = f2bf(f1); l.y = f2bf(f1 - bf2f(h.y));
    h.z = f2bf(f2); l.z = f2bf(f2 - bf2f(h.z));
    h.w = f2bf(f3); l.w = f2bf(f3 - bf2f(h.w));
    size_t o = (size_t)(n0 + n) * 1024 + k0 + c4;
    *(short4*)&Th[o] = h;
    *(short4*)&Tl[o] = l;
  }
}

// ------------------------------------------------------------- MFMA GEMM ----
// A (M x 1024) hi/lo bf16 row-major; Wt (N x 1024) hi/lo bf16 row-major.
// Block tile 64x64, 4 waves 2x2, wave tile 32x32, BK=32, bf16x3.
// EPI 0: split-K partial -> Of[(bz*R + rr)*N + col]  (no fences!)
// EPI 1: L4 — rows b*31+1+2u / +2+2u = tanh(bias -/+ acc) hi/lo + zero row at
//             u==0, plus per-row sumsq atomics into ns (prune-4 keys).
// EPI 2: L5 — raw fp32 out + per-row ||Y||^2 / dot(b5,Y) atomics.
template <int EPI, int D, int KS>
__global__ void __launch_bounds__(256, 2)
mfma_gemm(const short* __restrict__ Ah, const short* __restrict__ Al,
          const short* __restrict__ Bh, const short* __restrict__ Bl,
          const float* __restrict__ bias, short* __restrict__ Oh,
          short* __restrict__ Ol, float* __restrict__ Of,
          float* __restrict__ ns, float* __restrict__ dotv,
          float* __restrict__ nrmv, int N, int Dn) {
  constexpr int KC = 1024 / KS;
  constexpr int BKP = 40;  // pad: bank-quad stride 5 (coprime 8) -> <=2-way
  __shared__ short As_h[64 * BKP], As_l[64 * BKP];
  __shared__ short Bs_h[64 * BKP], Bs_l[64 * BKP];
  const int t = threadIdx.x;
  const int row0 = blockIdx.y * 64;
  const int col0 = blockIdx.x * 64;
  const int kb = blockIdx.z * KC;
  const int sr = t >> 2, sko = (t & 3) * 8;
  const short* Ahp = Ah + (size_t)(row0 + sr) * 1024 + kb + sko;
  const short* Alp = Al + (size_t)(row0 + sr) * 1024 + kb + sko;
  const short* Bhp = Bh + (size_t)(col0 + sr) * 1024 + kb + sko;
  const short* Blp = Bl + (size_t)(col0 + sr) * 1024 + kb + sko;
  const int w = t >> 6, lane = t & 63;
  const int l16 = lane & 15, q = lane >> 4;
  const int wm0 = (w & 1) * 32, wn0 = (w >> 1) * 32;
  const int abase = (wm0 + l16) * BKP + q * 8;
  const int bbase = (wn0 + l16) * BKP + q * 8;
  f4v acc[2][2];
#pragma unroll
  for (int i = 0; i < 2; ++i)
#pragma unroll
    for (int j = 0; j < 2; ++j) acc[i][j] = (f4v){0.f, 0.f, 0.f, 0.f};
  uint4 rah = *(const uint4*)(Ahp);
  uint4 ral = *(const uint4*)(Alp);
  uint4 rbh = *(const uint4*)(Bhp);
  uint4 rbl = *(const uint4*)(Blp);
  for (int k0 = 0; k0 < KC; k0 += 32) {
    __syncthreads();
    *(uint4*)&As_h[sr * BKP + sko] = rah;
    *(uint4*)&As_l[sr * BKP + sko] = ral;
    *(uint4*)&Bs_h[sr * BKP + sko] = rbh;
    *(uint4*)&Bs_l[sr * BKP + sko] = rbl;
    if (k0 + 32 < KC) {  // register prefetch of next slab
      rah = *(const uint4*)(Ahp + k0 + 32);
      ral = *(const uint4*)(Alp + k0 + 32);
      rbh = *(const uint4*)(Bhp + k0 + 32);
      rbl = *(const uint4*)(Blp + k0 + 32);
    }
    __syncthreads();
    s8v ah[2], al[2], bh[2], bl[2];
#pragma unroll
    for (int mt = 0; mt < 2; ++mt) {
      ah[mt] = *(const s8v*)&As_h[abase + mt * 16 * BKP];
      al[mt] = *(const s8v*)&As_l[abase + mt * 16 * BKP];
    }
#pragma unroll
    for (int nt = 0; nt < 2; ++nt) {
      bh[nt] = *(const s8v*)&Bs_h[bbase + nt * 16 * BKP];
      bl[nt] = *(const s8v*)&Bs_l[bbase + nt * 16 * BKP];
    }
#pragma unroll
    for (int mt = 0; mt < 2; ++mt)
#pragma unroll
      for (int nt = 0; nt < 2; ++nt) {
        acc[mt][nt] = __builtin_amdgcn_mfma_f32_16x16x32_bf16(
            ah[mt], bh[nt], acc[mt][nt], 0, 0, 0);
        acc[mt][nt] = __builtin_amdgcn_mfma_f32_16x16x32_bf16(
            ah[mt], bl[nt], acc[mt][nt], 0, 0, 0);
        acc[mt][nt] = __builtin_amdgcn_mfma_f32_16x16x32_bf16(
            al[mt], bh[nt], acc[mt][nt], 0, 0, 0);
      }
  }

  if constexpr (EPI == 0) {
    const int R = (int)gridDim.y << 6;
#pragma unroll
    for (int nt = 0; nt < 2; ++nt) {
      int gcol = col0 + wn0 + nt * 16 + l16;
#pragma unroll
      for (int mt = 0; mt < 2; ++mt)
#pragma unroll
        for (int r = 0; r < 4; ++r) {
          int rr = row0 + wm0 + mt * 16 + q * 4 + r;
          Of[((size_t)blockIdx.z * R + rr) * N + gcol] = acc[mt][nt][r];
        }
    }
  } else if constexpr (EPI == 1) {
    // L4: tanh± stores + per-row sumsq -> ns. D=15, Dn=31, N=1024.
    float bcr[2];
    int gc[2];
#pragma unroll
    for (int nt = 0; nt < 2; ++nt) {
      gc[nt] = col0 + wn0 + nt * 16 + l16;
      bcr[nt] = bias[gc[nt]];
    }
#pragma unroll
    for (int mt = 0; mt < 2; ++mt)
#pragma unroll
      for (int r = 0; r < 4; ++r) {
        int rr = row0 + wm0 + mt * 16 + q * 4 + r;
        int b = rr / D, u = rr - b * D;
        size_t ob = (size_t)(b * Dn) * (size_t)N;
        size_t om = ob + (size_t)(1 + 2 * u) * N;
        size_t op = ob + (size_t)(2 + 2 * u) * N;
        float sm = 0.f, sp = 0.f;
#pragma unroll
        for (int nt = 0; nt < 2; ++nt) {
          float v = acc[mt][nt][r];
          float tm = tanhf(bcr[nt] - v), tp = tanhf(bcr[nt] + v);
          split_store(tm, &Oh[om + gc[nt]], &Ol[om + gc[nt]]);
          split_store(tp, &Oh[op + gc[nt]], &Ol[op + gc[nt]]);
          sm = fmaf(tm, tm, sm);
          sp = fmaf(tp, tp, sp);
        }
#pragma unroll
        for (int msk = 1; msk < 16; msk <<= 1) {
          sm += __shfl_xor(sm, msk);
          sp += __shfl_xor(sp, msk);
        }
        if (l16 == 0) {
          atomicAdd(&ns[b * Dn + 1 + 2 * u], sm);
          atomicAdd(&ns[b * Dn + 2 + 2 * u], sp);
        }
        if (u == 0) {
          float sz = 0.f;
#pragma unroll
          for (int nt = 0; nt < 2; ++nt) {
            float tz = tanhf(bcr[nt]);
            split_store(tz, &Oh[ob + gc[nt]], &Ol[ob + gc[nt]]);
            sz = fmaf(tz, tz, sz);
          }
#pragma unroll
          for (int msk = 1; msk < 16; msk <<= 1) sz += __shfl_xor(sz, msk);
          if (l16 == 0) atomicAdd(&ns[b * Dn], sz);
        }
      }
  } else {
    // L5: raw fp32 out + ||Y||^2 and dot(b5,Y) atomics. bias == b5, N=512.
    float b5r[2];
    int gc[2];
#pragma unroll
    for (int nt = 0; nt < 2; ++nt) {
      gc[nt] = col0 + wn0 + nt * 16 + l16;
      b5r[nt] = bias[gc[nt]];
    }
#pragma unroll
    for (int mt = 0; mt < 2; ++mt)
#pragma unroll
      for (int r = 0; r < 4; ++r) {
        int rr = row0 + wm0 + mt * 16 + q * 4 + r;
        float nr = 0.f, dt = 0.f;
#pragma unroll
        for (int nt = 0; nt < 2; ++nt) {
          float v = acc[mt][nt][r];
          Of[(size_t)rr * N + gc[nt]] = v;
          nr = fmaf(v, v, nr);
          dt = fmaf(v, b5r[nt], dt);
        }
#pragma unroll
        for (int msk = 1; msk < 16; msk <<= 1) {
          nr += __shfl_xor(nr, msk);
          dt += __shfl_xor(dt, msk);
        }
        if (l16 == 0) {
          atomicAdd(&nrmv[rr], nr);
          atomicAdd(&dotv[rr], dt);
        }
      }
  }
}

// Combine split-K partials, layer 0: out = tanh(bias + sum) -> hi/lo.
template <int KS>
__global__ void __launch_bounds__(256)
comb0_hl(const float* __restrict__ P, const float* __restrict__ bias,
         short* __restrict__ Oh, short* __restrict__ Ol, int R, int N) {
  int i = blockIdx.x * 256 + threadIdx.x;
  int n4 = N >> 2;
  int r = i / n4, c4 = (i - r * n4) * 4;
  float4 y = *(const float4*)&P[(size_t)r * N + c4];
  size_t stride = (size_t)R * N;
#pragma unroll
  for (int ks = 1; ks < KS; ++ks) {
    const float4 p = *(const float4*)&P[ks * stride + (size_t)r * N + c4];
    y.x += p.x; y.y += p.y; y.z += p.z; y.w += p.w;
  }
  float4 bc = *(const float4*)(bias + c4);
  float t0 = tanhf(bc.x + y.x), t1 = tanhf(bc.y + y.y);
  float t2 = tanhf(bc.z + y.z), t3 = tanhf(bc.w + y.w);
  short4 h, l;
  h.x = f2bf(t0); l.x = f2bf(t0 - bf2f(h.x));
  h.y = f2bf(t1); l.y = f2bf(t1 - bf2f(h.y));
  h.z = f2bf(t2); l.z = f2bf(t2 - bf2f(h.z));
  h.w = f2bf(t3); l.w = f2bf(t3 - bf2f(h.w));
  *(short4*)&Oh[(size_t)r * N + c4] = h;
  *(short4*)&Ol[(size_t)r * N + c4] = l;
}

// Combine split-K partials, layers 1..3: rows b*Dn+1+2u (tanh(b-y)) and
// b*Dn+2+2u (tanh(b+y)); zero row tanh(b) at u==0. hi/lo out.
template <int KS, int D>
__global__ void __launch_bounds__(256)
comb1_hl(const float* __restrict__ P, const float* __restrict__ bias,
         short* __restrict__ Oh, short* __restrict__ Ol, int R, int N,
         int Dn) {
  int i = blockIdx.x * 256 + threadIdx.x;
  int n4 = N >> 2;
  int r = i / n4, c4 = (i - r * n4) * 4;
  int b = r / D, u = r - b * D;
  float4 y = *(const float4*)&P[(size_t)r * N + c4];
  size_t stride = (size_t)R * N;
#pragma unroll
  for (int ks = 1; ks < KS; ++ks) {
    const float4 p = *(const float4*)&P[ks * stride + (size_t)r * N + c4];
    y.x += p.x; y.y += p.y; y.z += p.z; y.w += p.w;
  }
  float4 bc = *(const float4*)(bias + c4);
  size_t ob = (size_t)(b * Dn) * N + c4;
  size_t om = ob + (size_t)(1 + 2 * u) * N;
  size_t op = ob + (size_t)(2 + 2 * u) * N;
  {
    float t0 = tanhf(bc.x - y.x), t1 = tanhf(bc.y - y.y);
    float t2 = tanhf(bc.z - y.z), t3 = tanhf(bc.w - y.w);
    short4 h, l;
    h.x = f2bf(t0); l.x = f2bf(t0 - bf2f(h.x));
    h.y = f2bf(t1); l.y = f2bf(t1 - bf2f(h.y));
    h.z = f2bf(t2); l.z = f2bf(t2 - bf2f(h.z));
    h.w = f2bf(t3); l.w = f2bf(t3 - bf2f(h.w));
    *(short4*)&Oh[om] = h;
    *(short4*)&Ol[om] = l;
  }
  {
    float t0 = tanhf(bc.x + y.x), t1 = tanhf(bc.y + y.y);
    float t2 = tanhf(bc.z + y.z), t3 = tanhf(bc.w + y.w);
    short4 h, l;
    h.x = f2bf(t0); l.x = f2bf(t0 - bf2f(h.x));
    h.y = f2bf(t1); l.y = f2bf(t1 - bf2f(h.y));
    h.z = f2bf(t2); l.z = f2bf(t2 - bf2f(h.z));
    h.w = f2bf(t3); l.w = f2bf(t3 - bf2f(h.w));
    *(short4*)&Oh[op] = h;
    *(short4*)&Ol[op] = l;
  }
  if (u == 0) {
    float t0 = tanhf(bc.x), t1 = tanhf(bc.y);
    float t2 = tanhf(bc.z), t3 = tanhf(bc.w);
    short4 h, l;
    h.x = f2bf(t0); l.x = f2bf(t0 - bf2f(h.x));
    h.y = f2bf(t1); l.y = f2bf(t1 - bf2f(h.y));
    h.z = f2bf(t2); l.z = f2bf(t2 - bf2f(h.z));
    h.w = f2bf(t3); l.w = f2bf(t3 - bf2f(h.w));
    *(short4*)&Oh[ob] = h;
    *(short4*)&Ol[ob] = l;
  }
}

// Prune after layer 4: 243 entries e = 3*j + t4; class via base-3 digit fold.
__global__ void __launch_bounds__(256)
prune4_k(const float* __restrict__ ns, int* __restrict__ kept4) {
  int b = blockIdx.x, t = threadIdx.x;
  __shared__ float nss[31];
  __shared__ float key[243];
  __shared__ int cls[243];
  if (t < 31) nss[t] = ns[b * 31 + t];
  __syncthreads();
  if (t < 243) {
    int j = t / 3, t4 = t - 3 * j;
    int d0 = j / 27, d1 = (j / 9) % 3, d2 = (j / 3) % 3, d3 = j % 3;
    int u = 0;
    u = (d0 == 1) ? 0 : (1 + 2 * u + (d0 == 2));
    u = (d1 == 1) ? 0 : (1 + 2 * u + (d1 == 2));
    u = (d2 == 1) ? 0 : (1 + 2 * u + (d2 == 2));
    u = (d3 == 1) ? 0 : (1 + 2 * u + (d3 == 2));
    cls[t] = u;
    key[t] = (t4 == 1) ? 0.f : nss[u];
  }
  __syncthreads();
  if (t < 243) {
    float k = key[t];
    int rank = 0;
    for (int e = 0; e < 243; ++e) {
      float ke = key[e];
      rank += (ke > k) || (ke == k && e < t);
    }
    if (rank < 128) {
      int t4 = t - 3 * (t / 3);
      kept4[b * 128 + rank] = (cls[t] << 1) | (t4 == 2 ? 1 : 0);
    }
  }
}

// Final prune 384->128. nb5 computed in-block (deterministic). Keys per
// (class,sign) computed once -> exact ties.
__global__ void __launch_bounds__(384)
prune5_k(const float* __restrict__ dotv, const float* __restrict__ nrmv,
         const float* __restrict__ b5, const int* __restrict__ kept4,
         int* __restrict__ kept5) {
  int b = blockIdx.x, t = threadIdx.x;
  __shared__ float red[384];
  __shared__ float pns[128];
  __shared__ float key[384];
  float p = 0.f;
  for (int o = t; o < 512; o += 384) p = fmaf(b5[o], b5[o], p);
  red[t] = p;
  __syncthreads();
  if (t < 128) red[t] = red[t] + red[t + 128] + red[t + 256];
  __syncthreads();
  if (t < 64) red[t] += red[t + 64];
  __syncthreads();
  if (t < 32) red[t] += red[t + 32];
  __syncthreads();
  if (t < 16) red[t] += red[t + 16];
  __syncthreads();
  if (t < 8) red[t] += red[t + 8];
  __syncthreads();
  if (t < 4) red[t] += red[t + 4];
  __syncthreads();
  if (t < 2) red[t] += red[t + 2];
  __syncthreads();
  if (t == 0) red[0] += red[1];
  __syncthreads();
  float nb5 = red[0];
  if (t < 128) {
    int k4 = kept4[b * 128 + t];
    int c = k4 >> 1;
    float s = (k4 & 1) ? 1.f : -1.f;
    pns[t] = nb5 + nrmv[b * 31 + c] + s * 2.f * dotv[b * 31 + c];
  }
  __syncthreads();
  int m = t / 3, tt = t - 3 * m;
  key[t] = (tt == 1) ? 0.f : pns[m];
  __syncthreads();
  float k = key[t];
  int rank = 0;
  for (int e = 0; e < 384; ++e) {
    float ke = key[e];
    rank += (ke > k) || (ke == k && e < t);
  }
  if (rank < 128) kept5[b * 128 + rank] = (m << 1) | (tt == 2 ? 1 : 0);
}

// Final data (B,512,128) + argmax-|.| output (B,512).
__global__ void __launch_bounds__(256)
finalize_k(const float* __restrict__ Y5, const float* __restrict__ b5,
           const int* __restrict__ kept4, const int* __restrict__ kept5,
           float* __restrict__ out, float* __restrict__ dataout) {
  const int b = blockIdx.y;
  const int o0 = blockIdx.x * 64;
  __shared__ float Ys[31][65];
  __shared__ float bias_s[64];
  __shared__ float vt[64][130];
  __shared__ float ra[64][4];
  __shared__ float rv[64][4];
  const int t = threadIdx.x;
  for (int idx = t; idx < 31 * 64; idx += 256) {
    int c = idx >> 6, o = idx & 63;
    Ys[c][o] = Y5[((size_t)b * 31 + c) * 512 + o0 + o];
  }
  if (t < 64) bias_s[t] = b5[o0 + t];
  const int rr = t & 127, oh = t >> 7;
  int k5 = kept5[b * 128 + rr];
  int m = k5 >> 1;
  float sig = (k5 & 1) ? 1.f : -1.f;
  int k4 = kept4[b * 128 + m];
  int cc = k4 >> 1;
  float s4 = (k4 & 1) ? 1.f : -1.f;
  float afac = sig * s4;
  __syncthreads();
#pragma unroll
  for (int ol = 0; ol < 32; ++ol) {
    int o = oh * 32 + ol;
    float v = sig * bias_s[o] + afac * Ys[cc][o];
    dataout[((size_t)b * 512 + o0 + o) * 128 + rr] = v;
    vt[o][rr] = v;
  }
  __syncthreads();
  int o = t >> 2, q = t & 3;
  float bestv = vt[o][q * 32];
  float besta = fabsf(bestv);
  for (int i = 1; i < 32; ++i) {
    float v = vt[o][q * 32 + i];
    float a = fabsf(v);
    if (a > besta) {
      besta = a;
      bestv = v;
    }
  }
  ra[o][q] = besta;
  rv[o][q] = bestv;
  __syncthreads();
  if (t < 64) {
    float ba = ra[t][0], bv = rv[t][0];
#pragma unroll
    for (int qq = 1; qq < 4; ++qq) {
      if (ra[t][qq] > ba) {
        ba = ra[t][qq];
        bv = rv[t][qq];
      }
    }
    out[(size_t)b * 512 + o0 + t] = bv;
  }
}

extern "C" void kernel_launch(void* const* d_in, const int* in_sizes, int n_in,
                              void* d_out, int out_size, void* d_ws,
                              size_t ws_size, hipStream_t stream) {
  const float* x = (const float*)d_in[0];
  const float* Wt[6];
  const float* bs[6];
  for (int i = 0; i < 6; ++i) {
    Wt[i] = (const float*)d_in[1 + 2 * i];
    bs[i] = (const float*)d_in[2 + 2 * i];
  }
  char* base = (char*)d_ws;
  // Aliases lifetime-disjoint in stream order (R4-proven):
  //   PA (partials L0-L2, <=6.3 MB) over C4h/C4l (first written at L3-comb)
  //   PB (partials L3, 7.34 MB)     over W0/W1   (dead after L1)
  //   C5h over W0..W1, C5l over W2..W3 (dead after L3); Y5 over C1..C4.
  short* A0h = (short*)(base + 0);
  short* A0l = (short*)(base + 262144);
  short* Wh[6], *Wl[6];
  {
    size_t off = 524288;
    for (int i = 0; i < 6; ++i) {
      size_t sz = (i < 5) ? 2097152 : 1048576;
      Wh[i] = (short*)(base + off);
      Wl[i] = (short*)(base + off + sz);
      off += 2 * sz;
    }
  }
  short* C1h = (short*)(base + 23592960), *C1l = (short*)(base + 23855104);
  short* C2h = (short*)(base + 24117248), *C2l = (short*)(base + 24903680);
  short* C3h = (short*)(base + 25690112), *C3l = (short*)(base + 27525120);
  short* C4h = (short*)(base + 29360128), *C4l = (short*)(base + 33292288);
  short* C5h = (short*)(base + 524288);
  short* C5l = (short*)(base + 8912896);
  float* PA = (float*)(base + 29360128);
  float* PB = (float*)(base + 524288);
  float* Y5 = (float*)(base + 23592960);
  float* ns = (float*)(base + 37224448);  // zone: 12288 floats
  float* dotv = ns + 3968;
  float* nrmv = dotv + 3968;
  int* kept4 = (int*)(base + 37273600);
  int* kept5 = (int*)(base + 37339136);
  float* outp = (float*)d_out;
  float* dataout = outp + 128 * 512;

  dim3 blk(256);
  TWArgs twa;
  for (int i = 0; i < 6; ++i) {
    twa.W[i] = Wt[i];
    twa.Th[i] = Wh[i];
    twa.Tl[i] = Wl[i];
  }
  twa.x = x;
  twa.A0h = A0h;
  twa.A0l = A0l;
  twa.zone = ns;
  transW_all<<<dim3(16, 16, 7), blk, 0, stream>>>(twa);

  // L0: x -> C1 (split-K 4)
  mfma_gemm<0, 1, 4><<<dim3(16, 2, 4), blk, 0, stream>>>(
      A0h, A0l, Wh[0], Wl[0], nullptr, nullptr, nullptr, PA, nullptr, nullptr,
      nullptr, 1024, 1);
  comb0_hl<4><<<dim3(128), blk, 0, stream>>>(PA, bs[0], C1h, C1l, 128, 1024);
  // L1: C1 -> C2 (split-K 4)
  mfma_gemm<0, 1, 4><<<dim3(16, 2, 4), blk, 0, stream>>>(
      C1h, C1l, Wh[1], Wl[1], nullptr, nullptr, nullptr, PA, nullptr, nullptr,
      nullptr, 1024, 3);
  comb1_hl<4, 1><<<dim3(128), blk, 0, stream>>>(PA, bs[1], C2h, C2l, 128, 1024,
                                                3);
  // L2: C2 (384) -> C3 (split-K 4)
  mfma_gemm<0, 3, 4><<<dim3(16, 6, 4), blk, 0, stream>>>(
      C2h, C2l, Wh[2], Wl[2], nullptr, nullptr, nullptr, PA, nullptr, nullptr,
      nullptr, 1024, 7);
  comb1_hl<4, 3><<<dim3(384), blk, 0, stream>>>(PA, bs[2], C3h, C3l, 384, 1024,
                                                7);
  // L3: C3 (896) -> C4 (split-K 2, partials in PB over dead W0/W1)
  mfma_gemm<0, 7, 2><<<dim3(16, 14, 2), blk, 0, stream>>>(
      C3h, C3l, Wh[3], Wl[3], nullptr, nullptr, nullptr, PB, nullptr, nullptr,
      nullptr, 1024, 15);
  comb1_hl<2, 7><<<dim3(896), blk, 0, stream>>>(PB, bs[3], C4h, C4l, 896, 1024,
                                                15);
  // L4: C4 (1920) -> C5 (3968) + fused ns sumsq atomics
  mfma_gemm<1, 15, 1><<<dim3(16, 30), blk, 0, stream>>>(
      C4h, C4l, Wh[4], Wl[4], bs[4], C5h, C5l, nullptr, ns, nullptr, nullptr,
      1024, 31);
  // Prune 243 -> 128
  prune4_k<<<dim3(128), blk, 0, stream>>>(ns, kept4);
  // L5: C5 -> Y5 raw fp32 (3968 x 512) + fused dot/nrm atomics
  mfma_gemm<2, 31, 1><<<dim3(8, 62), blk, 0, stream>>>(
      C5h, C5l, Wh[5], Wl[5], bs[5], nullptr, nullptr, Y5, nullptr, dotv, nrmv,
      512, 0);
  // Final prune + output
  prune5_k<<<dim3(128), dim3(384), 0, stream>>>(dotv, nrmv, bs[5], kept4,
                                                kept5);
  finalize_k<<<dim3(8, 128), blk, 0, stream>>>(Y5, bs[5], kept4, kept5, outp,
                                               dataout);
}

// Round 7
// 242.519 us; speedup vs baseline: 2.4309x; 1.0162x over previous
//
#include <hip/hip_runtime.h>
#include <math.h>

// PathPreservingNetwork — factored-class + bf16x3 MFMA, R7.
// Classes per layer input: 1,1,3,7,15,31; every path value is s*C[class].
// R7: R4's proven split-K/combine structure (no device fences) + LDS-transposed
// coalesced epilogues (R6's 2B/4B scattered stores caused L2 read-modify-write:
// FETCH 33 MB vs 12 MB input). Stats fused in the transposed store pass (one
// key per class => prune ties stay exact). LB(256,3) for 12 waves/CU.

using s8v = __attribute__((ext_vector_type(8))) short;
using f4v = __attribute__((ext_vector_type(4))) float;

__device__ __forceinline__ float bf2f(short b) {
  unsigned u = ((unsigned)(unsigned short)b) << 16;
  return __builtin_bit_cast(float, u);
}
__device__ __forceinline__ short f2bf(float f) {
  unsigned u = __builtin_bit_cast(unsigned, f);
  u = (u + 0x7FFFu + ((u >> 16) & 1u)) >> 16;
  return (short)u;
}

// Transpose+split all six W -> (N x 1024 bf16 hi/lo). z==6: blocks 0..127
// pack x (fp32 -> hi/lo); blocks 128..175 zero the ns/dotv/nrmv zone.
struct TWArgs {
  const float* W[6];
  short* Th[6];
  short* Tl[6];
  const float* x;
  short* A0h;
  short* A0l;
  float* zone;  // 12288 floats: ns(3968) dotv(3968) nrmv(3968) + pad
};
__global__ void __launch_bounds__(256)
transW_all(TWArgs a) {
  const int z = blockIdx.z;
  const int t = threadIdx.x;
  if (z == 6) {
    int bid = blockIdx.y * 16 + blockIdx.x;
    if (bid < 128) {
      int i = (bid * 256 + t) * 4;
      float4 v = *(const float4*)&a.x[i];
      short4 h, l;
      h.x = f2bf(v.x); l.x = f2bf(v.x - bf2f(h.x));
      h.y = f2bf(v.y); l.y = f2bf(v.y - bf2f(h.y));
      h.z = f2bf(v.z); l.z = f2bf(v.z - bf2f(h.z));
      h.w = f2bf(v.w); l.w = f2bf(v.w - bf2f(h.w));
      *(short4*)&a.A0h[i] = h;
      *(short4*)&a.A0l[i] = l;
    } else if (bid < 176) {
      a.zone[(bid - 128) * 256 + t] = 0.f;
    }
    return;
  }
  const int N = (z == 5) ? 512 : 1024;
  const int n0 = blockIdx.x * 64, k0 = blockIdx.y * 64;
  if (n0 >= N) return;
  const float* __restrict__ W = a.W[z];
  short* __restrict__ Th = a.Th[z];
  short* __restrict__ Tl = a.Tl[z];
  __shared__ float tile[64][65];
  const int r = t >> 4, c4 = (t & 15) * 4;
#pragma unroll
  for (int i = 0; i < 4; ++i) {
    int rr = r + 16 * i;
    float4 v = *(const float4*)&W[(size_t)(k0 + rr) * N + n0 + c4];
    tile[rr][c4 + 0] = v.x;
    tile[rr][c4 + 1] = v.y;
    tile[rr][c4 + 2] = v.z;
    tile[rr][c4 + 3] = v.w;
  }
  __syncthreads();
#pragma unroll
  for (int i = 0; i < 4; ++i) {
    int n = r + 16 * i;
    short4 h, l;
    float f0 = tile[c4 + 0][n], f1 = tile[c4 + 1][n];
    float f2 = tile[c4 + 2][n], f3 = tile[c4 + 3][n];
    h.x = f2bf(f0); l.x = f2bf(f0 - bf2f(h.x));
    h.y = f2bf(f1); l.y = f2bf(f1 - bf2f(h.y));
    h.z = f2bf(f2); l.z = f2bf(f2 - bf2f(h.z));
    h.w = f2bf(f3); l.w = f2bf(f3 - bf2f(h.w));
    size_t o = (size_t)(n0 + n) * 1024 + k0 + c4;
    *(short4*)&Th[o] = h;
    *(short4*)&Tl[o] = l;
  }
}

// ------------------------------------------------------------- MFMA GEMM ----
// A (M x 1024) hi/lo bf16 row-major; Wt (N x 1024) hi/lo bf16 row-major.
// Block tile 64x64, 4 waves 2x2, wave tile 32x32, BK=32, bf16x3.
// Epilogue: acc -> LDS transpose tile et[64][68]; thread t owns row t>>2 and
// 16-col chunk (t&3)*16 => a lane-quad covers one full 128 B line per row.
// EPI 0: split-K partial -> P[(bz*R + rr)*N + col]   (fp32, float4 stores)
// EPI 1: L4 — rows b*31+1+2u / +2+2u = tanh(bias -/+ acc) hi/lo (uint4
//         stores) + zero row at u==0; fused per-row sumsq atomics into ns.
// EPI 2: L5 — raw fp32 out (float4) + fused ||Y||^2 / dot(b5,Y) atomics.
template <int EPI, int D, int KS>
__global__ void __launch_bounds__(256, 3)
mfma_gemm(const short* __restrict__ Ah, const short* __restrict__ Al,
          const short* __restrict__ Bh, const short* __restrict__ Bl,
          const float* __restrict__ bias, short* __restrict__ Oh,
          short* __restrict__ Ol, float* __restrict__ Of,
          float* __restrict__ ns, float* __restrict__ dotv,
          float* __restrict__ nrmv, int N, int Dn) {
  constexpr int KC = 1024 / KS;
  constexpr int BKP = 40;  // pad: <=2-way LDS conflicts (free, m136)
  __shared__ short As_h[64 * BKP], As_l[64 * BKP];
  __shared__ short Bs_h[64 * BKP], Bs_l[64 * BKP];
  __shared__ float et[64][68];
  const int t = threadIdx.x;
  const int row0 = blockIdx.y * 64;
  const int col0 = blockIdx.x * 64;
  const int kb = blockIdx.z * KC;
  const int sr = t >> 2, sko = (t & 3) * 8;
  const short* Ahp = Ah + (size_t)(row0 + sr) * 1024 + kb + sko;
  const short* Alp = Al + (size_t)(row0 + sr) * 1024 + kb + sko;
  const short* Bhp = Bh + (size_t)(col0 + sr) * 1024 + kb + sko;
  const short* Blp = Bl + (size_t)(col0 + sr) * 1024 + kb + sko;
  const int w = t >> 6, lane = t & 63;
  const int l16 = lane & 15, q = lane >> 4;
  const int wm0 = (w & 1) * 32, wn0 = (w >> 1) * 32;
  const int abase = (wm0 + l16) * BKP + q * 8;
  const int bbase = (wn0 + l16) * BKP + q * 8;
  f4v acc[2][2];
#pragma unroll
  for (int i = 0; i < 2; ++i)
#pragma unroll
    for (int j = 0; j < 2; ++j) acc[i][j] = (f4v){0.f, 0.f, 0.f, 0.f};
  uint4 rah = *(const uint4*)(Ahp);
  uint4 ral = *(const uint4*)(Alp);
  uint4 rbh = *(const uint4*)(Bhp);
  uint4 rbl = *(const uint4*)(Blp);
  for (int k0 = 0; k0 < KC; k0 += 32) {
    __syncthreads();
    *(uint4*)&As_h[sr * BKP + sko] = rah;
    *(uint4*)&As_l[sr * BKP + sko] = ral;
    *(uint4*)&Bs_h[sr * BKP + sko] = rbh;
    *(uint4*)&Bs_l[sr * BKP + sko] = rbl;
    if (k0 + 32 < KC) {  // register prefetch of next slab
      rah = *(const uint4*)(Ahp + k0 + 32);
      ral = *(const uint4*)(Alp + k0 + 32);
      rbh = *(const uint4*)(Bhp + k0 + 32);
      rbl = *(const uint4*)(Blp + k0 + 32);
    }
    __syncthreads();
    s8v ah[2], al[2], bh[2], bl[2];
#pragma unroll
    for (int mt = 0; mt < 2; ++mt) {
      ah[mt] = *(const s8v*)&As_h[abase + mt * 16 * BKP];
      al[mt] = *(const s8v*)&As_l[abase + mt * 16 * BKP];
    }
#pragma unroll
    for (int nt = 0; nt < 2; ++nt) {
      bh[nt] = *(const s8v*)&Bs_h[bbase + nt * 16 * BKP];
      bl[nt] = *(const s8v*)&Bs_l[bbase + nt * 16 * BKP];
    }
#pragma unroll
    for (int mt = 0; mt < 2; ++mt)
#pragma unroll
      for (int nt = 0; nt < 2; ++nt) {
        acc[mt][nt] = __builtin_amdgcn_mfma_f32_16x16x32_bf16(
            ah[mt], bh[nt], acc[mt][nt], 0, 0, 0);
        acc[mt][nt] = __builtin_amdgcn_mfma_f32_16x16x32_bf16(
            ah[mt], bl[nt], acc[mt][nt], 0, 0, 0);
        acc[mt][nt] = __builtin_amdgcn_mfma_f32_16x16x32_bf16(
            al[mt], bh[nt], acc[mt][nt], 0, 0, 0);
      }
  }

  // acc -> LDS transpose (et is a separate buffer; no extra barrier needed).
#pragma unroll
  for (int mt = 0; mt < 2; ++mt)
#pragma unroll
    for (int nt = 0; nt < 2; ++nt)
#pragma unroll
      for (int r = 0; r < 4; ++r)
        et[wm0 + mt * 16 + q * 4 + r][wn0 + nt * 16 + l16] = acc[mt][nt][r];
  __syncthreads();
  const int rl = t >> 2, cc = (t & 3) * 16;
  float v[16];
#pragma unroll
  for (int j = 0; j < 16; ++j) v[j] = et[rl][cc + j];
  const int rr = row0 + rl;

  if constexpr (EPI == 0) {
    const int R = (int)gridDim.y << 6;
    float* dst = Of + ((size_t)blockIdx.z * R + rr) * N + col0 + cc;
#pragma unroll
    for (int i = 0; i < 4; ++i)
      *(float4*)&dst[4 * i] =
          make_float4(v[4 * i], v[4 * i + 1], v[4 * i + 2], v[4 * i + 3]);
  } else if constexpr (EPI == 1) {
    // L4: tanh± rows + zero row, coalesced uint4 stores, fused sumsq.
    const int b = rr / D, u = rr - b * D;
    const size_t ob = (size_t)(b * Dn) * (size_t)N + col0 + cc;
    const size_t om = ob + (size_t)(1 + 2 * u) * N;
    const size_t op = ob + (size_t)(2 + 2 * u) * N;
    uint mh[8], ml[8], ph[8], pl[8];
    float sm = 0.f, sp = 0.f;
#pragma unroll
    for (int j2 = 0; j2 < 8; ++j2) {
      float bc0 = bias[col0 + cc + 2 * j2];
      float bc1 = bias[col0 + cc + 2 * j2 + 1];
      float tm0 = tanhf(bc0 - v[2 * j2]), tm1 = tanhf(bc1 - v[2 * j2 + 1]);
      float tp0 = tanhf(bc0 + v[2 * j2]), tp1 = tanhf(bc1 + v[2 * j2 + 1]);
      short h0 = f2bf(tm0), h1 = f2bf(tm1);
      short g0 = f2bf(tm0 - bf2f(h0)), g1 = f2bf(tm1 - bf2f(h1));
      mh[j2] = (uint)(unsigned short)h0 | ((uint)(unsigned short)h1 << 16);
      ml[j2] = (uint)(unsigned short)g0 | ((uint)(unsigned short)g1 << 16);
      h0 = f2bf(tp0); h1 = f2bf(tp1);
      g0 = f2bf(tp0 - bf2f(h0)); g1 = f2bf(tp1 - bf2f(h1));
      ph[j2] = (uint)(unsigned short)h0 | ((uint)(unsigned short)h1 << 16);
      pl[j2] = (uint)(unsigned short)g0 | ((uint)(unsigned short)g1 << 16);
      sm = fmaf(tm0, tm0, fmaf(tm1, tm1, sm));
      sp = fmaf(tp0, tp0, fmaf(tp1, tp1, sp));
    }
    *(uint4*)&Oh[om] = make_uint4(mh[0], mh[1], mh[2], mh[3]);
    *(uint4*)&Oh[om + 8] = make_uint4(mh[4], mh[5], mh[6], mh[7]);
    *(uint4*)&Ol[om] = make_uint4(ml[0], ml[1], ml[2], ml[3]);
    *(uint4*)&Ol[om + 8] = make_uint4(ml[4], ml[5], ml[6], ml[7]);
    *(uint4*)&Oh[op] = make_uint4(ph[0], ph[1], ph[2], ph[3]);
    *(uint4*)&Oh[op + 8] = make_uint4(ph[4], ph[5], ph[6], ph[7]);
    *(uint4*)&Ol[op] = make_uint4(pl[0], pl[1], pl[2], pl[3]);
    *(uint4*)&Ol[op + 8] = make_uint4(pl[4], pl[5], pl[6], pl[7]);
    sm += __shfl_xor(sm, 1); sm += __shfl_xor(sm, 2);
    sp += __shfl_xor(sp, 1); sp += __shfl_xor(sp, 2);
    if ((t & 3) == 0) {
      atomicAdd(&ns[b * Dn + 1 + 2 * u], sm);
      atomicAdd(&ns[b * Dn + 2 + 2 * u], sp);
    }
    if (u == 0) {
      uint zh[8], zl[8];
      float sz = 0.f;
#pragma unroll
      for (int j2 = 0; j2 < 8; ++j2) {
        float tz0 = tanhf(bias[col0 + cc + 2 * j2]);
        float tz1 = tanhf(bias[col0 + cc + 2 * j2 + 1]);
        short h0 = f2bf(tz0), h1 = f2bf(tz1);
        short g0 = f2bf(tz0 - bf2f(h0)), g1 = f2bf(tz1 - bf2f(h1));
        zh[j2] = (uint)(unsigned short)h0 | ((uint)(unsigned short)h1 << 16);
        zl[j2] = (uint)(unsigned short)g0 | ((uint)(unsigned short)g1 << 16);
        sz = fmaf(tz0, tz0, fmaf(tz1, tz1, sz));
      }
      *(uint4*)&Oh[ob] = make_uint4(zh[0], zh[1], zh[2], zh[3]);
      *(uint4*)&Oh[ob + 8] = make_uint4(zh[4], zh[5], zh[6], zh[7]);
      *(uint4*)&Ol[ob] = make_uint4(zl[0], zl[1], zl[2], zl[3]);
      *(uint4*)&Ol[ob + 8] = make_uint4(zl[4], zl[5], zl[6], zl[7]);
      sz += __shfl_xor(sz, 1); sz += __shfl_xor(sz, 2);
      if ((t & 3) == 0) atomicAdd(&ns[b * Dn], sz);
    }
  } else {
    // L5: raw fp32 out + fused ||Y||^2 / dot(b5,Y). bias == b5, N=512.
    float nr = 0.f, dt = 0.f;
    float* dst = Of + (size_t)rr * N + col0 + cc;
#pragma unroll
    for (int j = 0; j < 16; ++j) {
      nr = fmaf(v[j], v[j], nr);
      dt = fmaf(v[j], bias[col0 + cc + j], dt);
    }
#pragma unroll
    for (int i = 0; i < 4; ++i)
      *(float4*)&dst[4 * i] =
          make_float4(v[4 * i], v[4 * i + 1], v[4 * i + 2], v[4 * i + 3]);
    nr += __shfl_xor(nr, 1); nr += __shfl_xor(nr, 2);
    dt += __shfl_xor(dt, 1); dt += __shfl_xor(dt, 2);
    if ((t & 3) == 0) {
      atomicAdd(&nrmv[rr], nr);
      atomicAdd(&dotv[rr], dt);
    }
  }
}

// Combine split-K partials, layer 0: out = tanh(bias + sum) -> hi/lo.
template <int KS>
__global__ void __launch_bounds__(256)
comb0_hl(const float* __restrict__ P, const float* __restrict__ bias,
         short* __restrict__ Oh, short* __restrict__ Ol, int R, int N) {
  int i = blockIdx.x * 256 + threadIdx.x;
  int n4 = N >> 2;
  int r = i / n4, c4 = (i - r * n4) * 4;
  float4 y = *(const float4*)&P[(size_t)r * N + c4];
  size_t stride = (size_t)R * N;
#pragma unroll
  for (int ks = 1; ks < KS; ++ks) {
    const float4 p = *(const float4*)&P[ks * stride + (size_t)r * N + c4];
    y.x += p.x; y.y += p.y; y.z += p.z; y.w += p.w;
  }
  float4 bc = *(const float4*)(bias + c4);
  float t0 = tanhf(bc.x + y.x), t1 = tanhf(bc.y + y.y);
  float t2 = tanhf(bc.z + y.z), t3 = tanhf(bc.w + y.w);
  short4 h, l;
  h.x = f2bf(t0); l.x = f2bf(t0 - bf2f(h.x));
  h.y = f2bf(t1); l.y = f2bf(t1 - bf2f(h.y));
  h.z = f2bf(t2); l.z = f2bf(t2 - bf2f(h.z));
  h.w = f2bf(t3); l.w = f2bf(t3 - bf2f(h.w));
  *(short4*)&Oh[(size_t)r * N + c4] = h;
  *(short4*)&Ol[(size_t)r * N + c4] = l;
}

// Combine split-K partials, layers 1..3: rows b*Dn+1+2u (tanh(b-y)) and
// b*Dn+2+2u (tanh(b+y)); zero row tanh(b) at u==0. hi/lo out.
template <int KS, int D>
__global__ void __launch_bounds__(256)
comb1_hl(const float* __restrict__ P, const float* __restrict__ bias,
         short* __restrict__ Oh, short* __restrict__ Ol, int R, int N,
         int Dn) {
  int i = blockIdx.x * 256 + threadIdx.x;
  int n4 = N >> 2;
  int r = i / n4, c4 = (i - r * n4) * 4;
  int b = r / D, u = r - b * D;
  float4 y = *(const float4*)&P[(size_t)r * N + c4];
  size_t stride = (size_t)R * N;
#pragma unroll
  for (int ks = 1; ks < KS; ++ks) {
    const float4 p = *(const float4*)&P[ks * stride + (size_t)r * N + c4];
    y.x += p.x; y.y += p.y; y.z += p.z; y.w += p.w;
  }
  float4 bc = *(const float4*)(bias + c4);
  size_t ob = (size_t)(b * Dn) * N + c4;
  size_t om = ob + (size_t)(1 + 2 * u) * N;
  size_t op = ob + (size_t)(2 + 2 * u) * N;
  {
    float t0 = tanhf(bc.x - y.x), t1 = tanhf(bc.y - y.y);
    float t2 = tanhf(bc.z - y.z), t3 = tanhf(bc.w - y.w);
    short4 h, l;
    h.x = f2bf(t0); l.x = f2bf(t0 - bf2f(h.x));
    h.y = f2bf(t1); l.y = f2bf(t1 - bf2f(h.y));
    h.z = f2bf(t2); l.z = f2bf(t2 - bf2f(h.z));
    h.w = f2bf(t3); l.w = f2bf(t3 - bf2f(h.w));
    *(short4*)&Oh[om] = h;
    *(short4*)&Ol[om] = l;
  }
  {
    float t0 = tanhf(bc.x + y.x), t1 = tanhf(bc.y + y.y);
    float t2 = tanhf(bc.z + y.z), t3 = tanhf(bc.w + y.w);
    short4 h, l;
    h.x = f2bf(t0); l.x = f2bf(t0 - bf2f(h.x));
    h.y = f2bf(t1); l.y = f2bf(t1 - bf2f(h.y));
    h.z = f2bf(t2); l.z = f2bf(t2 - bf2f(h.z));
    h.w = f2bf(t3); l.w = f2bf(t3 - bf2f(h.w));
    *(short4*)&Oh[op] = h;
    *(short4*)&Ol[op] = l;
  }
  if (u == 0) {
    float t0 = tanhf(bc.x), t1 = tanhf(bc.y);
    float t2 = tanhf(bc.z), t3 = tanhf(bc.w);
    short4 h, l;
    h.x = f2bf(t0); l.x = f2bf(t0 - bf2f(h.x));
    h.y = f2bf(t1); l.y = f2bf(t1 - bf2f(h.y));
    h.z = f2bf(t2); l.z = f2bf(t2 - bf2f(h.z));
    h.w = f2bf(t3); l.w = f2bf(t3 - bf2f(h.w));
    *(short4*)&Oh[ob] = h;
    *(short4*)&Ol[ob] = l;
  }
}

// Prune after layer 4: 243 entries e = 3*j + t4; class via base-3 digit fold.
__global__ void __launch_bounds__(256)
prune4_k(const float* __restrict__ ns, int* __restrict__ kept4) {
  int b = blockIdx.x, t = threadIdx.x;
  __shared__ float nss[31];
  __shared__ float key[243];
  __shared__ int cls[243];
  if (t < 31) nss[t] = ns[b * 31 + t];
  __syncthreads();
  if (t < 243) {
    int j = t / 3, t4 = t - 3 * j;
    int d0 = j / 27, d1 = (j / 9) % 3, d2 = (j / 3) % 3, d3 = j % 3;
    int u = 0;
    u = (d0 == 1) ? 0 : (1 + 2 * u + (d0 == 2));
    u = (d1 == 1) ? 0 : (1 + 2 * u + (d1 == 2));
    u = (d2 == 1) ? 0 : (1 + 2 * u + (d2 == 2));
    u = (d3 == 1) ? 0 : (1 + 2 * u + (d3 == 2));
    cls[t] = u;
    key[t] = (t4 == 1) ? 0.f : nss[u];
  }
  __syncthreads();
  if (t < 243) {
    float k = key[t];
    int rank = 0;
    for (int e = 0; e < 243; ++e) {
      float ke = key[e];
      rank += (ke > k) || (ke == k && e < t);
    }
    if (rank < 128) {
      int t4 = t - 3 * (t / 3);
      kept4[b * 128 + rank] = (cls[t] << 1) | (t4 == 2 ? 1 : 0);
    }
  }
}

// Final prune 384->128. nb5 computed in-block (deterministic). Keys per
// (class,sign) computed once -> exact ties.
__global__ void __launch_bounds__(384)
prune5_k(const float* __restrict__ dotv, const float* __restrict__ nrmv,
         const float* __restrict__ b5, const int* __restrict__ kept4,
         int* __restrict__ kept5) {
  int b = blockIdx.x, t = threadIdx.x;
  __shared__ float red[384];
  __shared__ float pns[128];
  __shared__ float key[384];
  float p = 0.f;
  for (int o = t; o < 512; o += 384) p = fmaf(b5[o], b5[o], p);
  red[t] = p;
  __syncthreads();
  if (t < 128) red[t] = red[t] + red[t + 128] + red[t + 256];
  __syncthreads();
  if (t < 64) red[t] += red[t + 64];
  __syncthreads();
  if (t < 32) red[t] += red[t + 32];
  __syncthreads();
  if (t < 16) red[t] += red[t + 16];
  __syncthreads();
  if (t < 8) red[t] += red[t + 8];
  __syncthreads();
  if (t < 4) red[t] += red[t + 4];
  __syncthreads();
  if (t < 2) red[t] += red[t + 2];
  __syncthreads();
  if (t == 0) red[0] += red[1];
  __syncthreads();
  float nb5 = red[0];
  if (t < 128) {
    int k4 = kept4[b * 128 + t];
    int c = k4 >> 1;
    float s = (k4 & 1) ? 1.f : -1.f;
    pns[t] = nb5 + nrmv[b * 31 + c] + s * 2.f * dotv[b * 31 + c];
  }
  __syncthreads();
  int m = t / 3, tt = t - 3 * m;
  key[t] = (tt == 1) ? 0.f : pns[m];
  __syncthreads();
  float k = key[t];
  int rank = 0;
  for (int e = 0; e < 384; ++e) {
    float ke = key[e];
    rank += (ke > k) || (ke == k && e < t);
  }
  if (rank < 128) kept5[b * 128 + rank] = (m << 1) | (tt == 2 ? 1 : 0);
}

// Final data (B,512,128) + argmax-|.| output (B,512).
__global__ void __launch_bounds__(256)
finalize_k(const float* __restrict__ Y5, const float* __restrict__ b5,
           const int* __restrict__ kept4, const int* __restrict__ kept5,
           float* __restrict__ out, float* __restrict__ dataout) {
  const int b = blockIdx.y;
  const int o0 = blockIdx.x * 64;
  __shared__ float Ys[31][65];
  __shared__ float bias_s[64];
  __shared__ float vt[64][130];
  __shared__ float ra[64][4];
  __shared__ float rv[64][4];
  const int t = threadIdx.x;
  for (int idx = t; idx < 31 * 64; idx += 256) {
    int c = idx >> 6, o = idx & 63;
    Ys[c][o] = Y5[((size_t)b * 31 + c) * 512 + o0 + o];
  }
  if (t < 64) bias_s[t] = b5[o0 + t];
  const int rr = t & 127, oh = t >> 7;
  int k5 = kept5[b * 128 + rr];
  int m = k5 >> 1;
  float sig = (k5 & 1) ? 1.f : -1.f;
  int k4 = kept4[b * 128 + m];
  int cc = k4 >> 1;
  float s4 = (k4 & 1) ? 1.f : -1.f;
  float afac = sig * s4;
  __syncthreads();
#pragma unroll
  for (int ol = 0; ol < 32; ++ol) {
    int o = oh * 32 + ol;
    float v = sig * bias_s[o] + afac * Ys[cc][o];
    dataout[((size_t)b * 512 + o0 + o) * 128 + rr] = v;
    vt[o][rr] = v;
  }
  __syncthreads();
  int o = t >> 2, q = t & 3;
  float bestv = vt[o][q * 32];
  float besta = fabsf(bestv);
  for (int i = 1; i < 32; ++i) {
    float v = vt[o][q * 32 + i];
    float a = fabsf(v);
    if (a > besta) {
      besta = a;
      bestv = v;
    }
  }
  ra[o][q] = besta;
  rv[o][q] = bestv;
  __syncthreads();
  if (t < 64) {
    float ba = ra[t][0], bv = rv[t][0];
#pragma unroll
    for (int qq = 1; qq < 4; ++qq) {
      if (ra[t][qq] > ba) {
        ba = ra[t][qq];
        bv = rv[t][qq];
      }
    }
    out[(size_t)b * 512 + o0 + t] = bv;
  }
}

extern "C" void kernel_launch(void* const* d_in, const int* in_sizes, int n_in,
                              void* d_out, int out_size, void* d_ws,
                              size_t ws_size, hipStream_t stream) {
  const float* x = (const float*)d_in[0];
  const float* Wt[6];
  const float* bs[6];
  for (int i = 0; i < 6; ++i) {
    Wt[i] = (const float*)d_in[1 + 2 * i];
    bs[i] = (const float*)d_in[2 + 2 * i];
  }
  char* base = (char*)d_ws;
  // Aliases lifetime-disjoint in stream order (R4-proven):
  //   PA (partials L0-L2, <=6.3 MB) over C4h/C4l (first written at L3-comb)
  //   PB (partials L3, 7.34 MB)     over W0/W1   (dead after L1)
  //   C5h over W0..W1, C5l over W2..W3 (dead after L3); Y5 over C1..C4.
  short* A0h = (short*)(base + 0);
  short* A0l = (short*)(base + 262144);
  short* Wh[6], *Wl[6];
  {
    size_t off = 524288;
    for (int i = 0; i < 6; ++i) {
      size_t sz = (i < 5) ? 2097152 : 1048576;
      Wh[i] = (short*)(base + off);
      Wl[i] = (short*)(base + off + sz);
      off += 2 * sz;
    }
  }
  short* C1h = (short*)(base + 23592960), *C1l = (short*)(base + 23855104);
  short* C2h = (short*)(base + 24117248), *C2l = (short*)(base + 24903680);
  short* C3h = (short*)(base + 25690112), *C3l = (short*)(base + 27525120);
  short* C4h = (short*)(base + 29360128), *C4l = (short*)(base + 33292288);
  short* C5h = (short*)(base + 524288);
  short* C5l = (short*)(base + 8912896);
  float* PA = (float*)(base + 29360128);
  float* PB = (float*)(base + 524288);
  float* Y5 = (float*)(base + 23592960);
  float* ns = (float*)(base + 37224448);  // zone: 12288 floats
  float* dotv = ns + 3968;
  float* nrmv = dotv + 3968;
  int* kept4 = (int*)(base + 37273600);
  int* kept5 = (int*)(base + 37339136);
  float* outp = (float*)d_out;
  float* dataout = outp + 128 * 512;

  dim3 blk(256);
  TWArgs twa;
  for (int i = 0; i < 6; ++i) {
    twa.W[i] = Wt[i];
    twa.Th[i] = Wh[i];
    twa.Tl[i] = Wl[i];
  }
  twa.x = x;
  twa.A0h = A0h;
  twa.A0l = A0l;
  twa.zone = ns;
  transW_all<<<dim3(16, 16, 7), blk, 0, stream>>>(twa);

  // L0: x -> C1 (split-K 8; 256 blocks)
  mfma_gemm<0, 1, 8><<<dim3(16, 2, 8), blk, 0, stream>>>(
      A0h, A0l, Wh[0], Wl[0], nullptr, nullptr, nullptr, PA, nullptr, nullptr,
      nullptr, 1024, 1);
  comb0_hl<8><<<dim3(128), blk, 0, stream>>>(PA, bs[0], C1h, C1l, 128, 1024);
  // L1: C1 -> C2 (split-K 8)
  mfma_gemm<0, 1, 8><<<dim3(16, 2, 8), blk, 0, stream>>>(
      C1h, C1l, Wh[1], Wl[1], nullptr, nullptr, nullptr, PA, nullptr, nullptr,
      nullptr, 1024, 3);
  comb1_hl<8, 1><<<dim3(128), blk, 0, stream>>>(PA, bs[1], C2h, C2l, 128, 1024,
                                                3);
  // L2: C2 (384) -> C3 (split-K 4)
  mfma_gemm<0, 3, 4><<<dim3(16, 6, 4), blk, 0, stream>>>(
      C2h, C2l, Wh[2], Wl[2], nullptr, nullptr, nullptr, PA, nullptr, nullptr,
      nullptr, 1024, 7);
  comb1_hl<4, 3><<<dim3(384), blk, 0, stream>>>(PA, bs[2], C3h, C3l, 384, 1024,
                                                7);
  // L3: C3 (896) -> C4 (split-K 2, partials in PB over dead W0/W1)
  mfma_gemm<0, 7, 2><<<dim3(16, 14, 2), blk, 0, stream>>>(
      C3h, C3l, Wh[3], Wl[3], nullptr, nullptr, nullptr, PB, nullptr, nullptr,
      nullptr, 1024, 15);
  comb1_hl<2, 7><<<dim3(896), blk, 0, stream>>>(PB, bs[3], C4h, C4l, 896, 1024,
                                                15);
  // L4: C4 (1920) -> C5 (3968) + fused ns sumsq (coalesced epilogue)
  mfma_gemm<1, 15, 1><<<dim3(16, 30), blk, 0, stream>>>(
      C4h, C4l, Wh[4], Wl[4], bs[4], C5h, C5l, nullptr, ns, nullptr, nullptr,
      1024, 31);
  // Prune 243 -> 128
  prune4_k<<<dim3(128), blk, 0, stream>>>(ns, kept4);
  // L5: C5 -> Y5 raw fp32 (3968 x 512) + fused dot/nrm (coalesced epilogue)
  mfma_gemm<2, 31, 1><<<dim3(8, 62), blk, 0, stream>>>(
      C5h, C5l, Wh[5], Wl[5], bs[5], nullptr, nullptr, Y5, nullptr, dotv, nrmv,
      512, 0);
  // Final prune + output
  prune5_k<<<dim3(128), dim3(384), 0, stream>>>(dotv, nrmv, bs[5], kept4,
                                                kept5);
  finalize_k<<<dim3(8, 128), blk, 0, stream>>>(Y5, bs[5], kept4, kept5, outp,
                                               dataout);
}